// Round 18
// 114.259 us; speedup vs baseline: 2.6721x; 1.0001x over previous
//
#include <hip/hip_runtime.h>
#include <hip/hip_bf16.h>

typedef unsigned short u16;
typedef unsigned int u32;
typedef _Float16 f16;
typedef __attribute__((ext_vector_type(8))) __bf16 bf16x8;
typedef __attribute__((ext_vector_type(4))) float f32x4;

#define LOG2E 1.44269504088896340736f

__device__ inline u16 f2bf(float f) {
  unsigned int x = __float_as_uint(f);
  unsigned int r = (x + 0x7FFFu + ((x >> 16) & 1u)) >> 16;
  return (u16)r;
}
__device__ inline float bf2f(u16 u) { return __uint_as_float(((unsigned int)u) << 16); }
__device__ inline void split2(float v, u16& h, u16& l) {
  h = f2bf(v);
  l = f2bf(v - bf2f(h));
}
__device__ inline u32 cvt_pk_bf16(float lo, float hi) {
  u32 r;
  asm("v_cvt_pk_bf16_f32 %0, %1, %2" : "=v"(r) : "v"(lo), "v"(hi));
  return r;
}
__device__ inline float exp2_fast(float x) {
  float r;
  asm("v_exp_f32 %0, %1" : "=v"(r) : "v"(x));
  return r;
}
// async global->LDS, 16B/lane; dest = wave-uniform base + lane*16
__device__ inline void gll16(const u16* g, u16* l) {
  __builtin_amdgcn_global_load_lds((const __attribute__((address_space(1))) void*)g,
                                   (__attribute__((address_space(3))) void*)l, 16, 0, 0);
}
// [R][32]-bf16 tile (64B rows): logical (row, slot s in 0..3) -> physical byte offset
#define TOFF(r, s) (((r) << 6) + ((((s) ^ (((r) >> 1) & 3))) << 4))
// [R][64]-bf16 tile (128B rows): logical (row, slot s in 0..7) -> physical byte offset
#define TOFF2(r, s) (((r) << 7) + ((((s) ^ ((r) & 7))) << 4))

// ---------------- fused: x transpose + weight prep + stats zeroing ----------------
__global__ __launch_bounds__(256) void prep_all(
    const float* __restrict__ x,
    const float* __restrict__ Wq, const float* __restrict__ Wk, const float* __restrict__ Wv,
    const float* __restrict__ bq, const float* __restrict__ bk,
    const float* __restrict__ W2,
    u16* __restrict__ XtbH, u16* __restrict__ XtbL,
    u16* __restrict__ WallH, u16* __restrict__ WallL,
    u16* __restrict__ WvH, u16* __restrict__ WvL,
    u16* __restrict__ W2b,
    float* __restrict__ bqk, float* __restrict__ statsZ) {
  __shared__ float tile[32][33];
  const int id = blockIdx.x;
  if (id < 4096) {
    int n0 = (id & 31) * 32, c0 = ((id >> 5) & 7) * 32, b = id >> 8;
    int tx = threadIdx.x & 31, ty = threadIdx.x >> 5;
#pragma unroll
    for (int j = 0; j < 4; ++j) {
      int c = c0 + ty + j * 8;
      tile[ty + j * 8][tx] = x[((size_t)b * 256 + c) * 1024 + n0 + tx];
    }
    __syncthreads();
#pragma unroll
    for (int j = 0; j < 4; ++j) {
      int n = n0 + ty + j * 8;
      float v = tile[tx][ty + j * 8];
      size_t o = ((size_t)b * 1024 + n) * 256 + c0 + tx;
      u16 h, l;
      split2(v, h, l);
      XtbH[o] = h; XtbL[o] = l;
    }
  } else {
    int i = (id - 4096) * 256 + threadIdx.x;
    if (i < 2048) statsZ[i] = 0.f;   // stats1|pad|stats2|pad (runs before attn/ffn2 atomics)
    if (i < 131072) {
      float w = (i < 65536) ? Wq[i] : Wk[i - 65536];
      u16 h, l;
      split2(w, h, l);
      WallH[i] = h; WallL[i] = l;
    }
    if (i < 65536) {
      u16 h, l;
      split2(Wv[i], h, l);
      WvH[i] = h; WvL[i] = l;
    }
    if (i < 262144) W2b[i] = f2bf(W2[i]);
    if (i < 256) bqk[i] = bq[i];
    else if (i < 512) bqk[i] = bk[i - 256];
  }
}

// ---------------- fused QK-projection + V-projection (one dispatch, role by id) ----------
// Q-half outputs are pre-scaled by log2(e) so attention softmax can use raw v_exp_f32.
__global__ __launch_bounds__(256) void gemm_qkvt(
    const u16* __restrict__ Ah_, const u16* __restrict__ Al_,
    const u16* __restrict__ Bh_, const u16* __restrict__ Bl_,
    const float* __restrict__ bias,
    u16* __restrict__ Ch, u16* __restrict__ Cl,
    const u16* __restrict__ WvH_, const u16* __restrict__ WvL_,
    const float* __restrict__ bv, u16* __restrict__ Vt) {
  __shared__ u16 Ah[4096], Al[4096], Bh[4096], Bl[4096];
  const int tid = threadIdx.x;
  const int lane = tid & 63, w = tid >> 6;
  const int wr = w >> 1, wc = w & 1;
  const int q = lane & 15, G = lane >> 4;
  const int rr0 = w * 32 + (lane >> 2), rr1 = rr0 + 16;
  const int sl0 = (lane & 3) ^ ((rr0 >> 1) & 3);
  const int sl1 = (lane & 3) ^ ((rr1 >> 1) & 3);

  if (blockIdx.x < 512) {
    // ---- QK role ----
    const int eff = (blockIdx.x & 7) * 64 + (blockIdx.x >> 3);
    const int m0 = (eff >> 2) * 128, n0 = (eff & 3) * 128;
    const bool isQ = (n0 < 256);
    const size_t a0 = (size_t)(m0 + rr0) * 256 + sl0 * 8;
    const size_t a1 = (size_t)(m0 + rr1) * 256 + sl1 * 8;
    const size_t b0 = (size_t)(n0 + rr0) * 256 + sl0 * 8;
    const size_t b1 = (size_t)(n0 + rr1) * 256 + sl1 * 8;

    f32x4 acc[4][4] = {};
    for (int kt = 0; kt < 256; kt += 32) {
      __syncthreads();
      gll16(Ah_ + a0 + kt, &Ah[w * 1024]);
      gll16(Ah_ + a1 + kt, &Ah[w * 1024 + 512]);
      gll16(Al_ + a0 + kt, &Al[w * 1024]);
      gll16(Al_ + a1 + kt, &Al[w * 1024 + 512]);
      gll16(Bh_ + b0 + kt, &Bh[w * 1024]);
      gll16(Bh_ + b1 + kt, &Bh[w * 1024 + 512]);
      gll16(Bl_ + b0 + kt, &Bl[w * 1024]);
      gll16(Bl_ + b1 + kt, &Bl[w * 1024 + 512]);
      __syncthreads();
      bf16x8 afh[4], afl[4], bfh[4], bfl[4];
#pragma unroll
      for (int m = 0; m < 4; ++m) {
        int off = TOFF(wr * 64 + m * 16 + q, G);
        afh[m] = *reinterpret_cast<const bf16x8*>((const char*)Ah + off);
        afl[m] = *reinterpret_cast<const bf16x8*>((const char*)Al + off);
      }
#pragma unroll
      for (int n = 0; n < 4; ++n) {
        int off = TOFF(wc * 64 + n * 16 + q, G);
        bfh[n] = *reinterpret_cast<const bf16x8*>((const char*)Bh + off);
        bfl[n] = *reinterpret_cast<const bf16x8*>((const char*)Bl + off);
      }
#pragma unroll
      for (int m = 0; m < 4; ++m)
#pragma unroll
        for (int n = 0; n < 4; ++n) {
          acc[m][n] = __builtin_amdgcn_mfma_f32_16x16x32_bf16(afh[m], bfh[n], acc[m][n], 0, 0, 0);
          acc[m][n] = __builtin_amdgcn_mfma_f32_16x16x32_bf16(afl[m], bfh[n], acc[m][n], 0, 0, 0);
        }
      if (isQ) {
#pragma unroll
        for (int m = 0; m < 4; ++m)
#pragma unroll
          for (int n = 0; n < 4; ++n)
            acc[m][n] = __builtin_amdgcn_mfma_f32_16x16x32_bf16(afh[m], bfl[n], acc[m][n], 0, 0, 0);
      }
    }
    const float qscale = isQ ? LOG2E : 1.f;
#pragma unroll
    for (int m = 0; m < 4; ++m) {
      int row_b = m0 + wr * 64 + m * 16 + G * 4;
#pragma unroll
      for (int n = 0; n < 4; ++n) {
        int col = n0 + wc * 64 + n * 16 + q;
        float bb = bias[col];
#pragma unroll
        for (int r = 0; r < 4; ++r) {
          size_t o = (size_t)(row_b + r) * 512 + col;
          u16 h, l;
          split2((acc[m][n][r] + bb) * qscale, h, l);
          Ch[o] = h;
          if (isQ) Cl[o] = l;
        }
      }
    }
  } else {
    // ---- Vt role ----
    const int o_ = blockIdx.x - 512;
    const int eff = (o_ & 7) * 32 + (o_ >> 3);
    const int m0 = (eff & 1) * 128, n0 = ((eff >> 1) & 7) * 128, b = eff >> 4;
    const u16* Bp = Ah_ + (size_t)b * 1024 * 256;  // XtbH
    const size_t a0 = (size_t)(m0 + rr0) * 256 + sl0 * 8;
    const size_t a1 = (size_t)(m0 + rr1) * 256 + sl1 * 8;
    const size_t b0 = (size_t)(n0 + rr0) * 256 + sl0 * 8;
    const size_t b1 = (size_t)(n0 + rr1) * 256 + sl1 * 8;

    f32x4 acc[4][4] = {};
    for (int kt = 0; kt < 256; kt += 32) {
      __syncthreads();
      gll16(WvH_ + a0 + kt, &Ah[w * 1024]);
      gll16(WvH_ + a1 + kt, &Ah[w * 1024 + 512]);
      gll16(WvL_ + a0 + kt, &Al[w * 1024]);
      gll16(WvL_ + a1 + kt, &Al[w * 1024 + 512]);
      gll16(Bp + b0 + kt, &Bh[w * 1024]);
      gll16(Bp + b1 + kt, &Bh[w * 1024 + 512]);
      __syncthreads();
      bf16x8 afh[4], afl[4], bfr[4];
#pragma unroll
      for (int m = 0; m < 4; ++m) {
        int off = TOFF(wr * 64 + m * 16 + q, G);
        afh[m] = *reinterpret_cast<const bf16x8*>((const char*)Ah + off);
        afl[m] = *reinterpret_cast<const bf16x8*>((const char*)Al + off);
      }
#pragma unroll
      for (int n = 0; n < 4; ++n)
        bfr[n] = *reinterpret_cast<const bf16x8*>((const char*)Bh + TOFF(wc * 64 + n * 16 + q, G));
#pragma unroll
      for (int m = 0; m < 4; ++m)
#pragma unroll
        for (int n = 0; n < 4; ++n) {
          acc[m][n] = __builtin_amdgcn_mfma_f32_16x16x32_bf16(afh[m], bfr[n], acc[m][n], 0, 0, 0);
          acc[m][n] = __builtin_amdgcn_mfma_f32_16x16x32_bf16(afl[m], bfr[n], acc[m][n], 0, 0, 0);
        }
    }
#pragma unroll
    for (int m = 0; m < 4; ++m) {
      int row_b = m0 + wr * 64 + m * 16 + G * 4;  // d index
#pragma unroll
      for (int n = 0; n < 4; ++n) {
        int col = n0 + wc * 64 + n * 16 + q;      // token n
#pragma unroll
        for (int r = 0; r < 4; ++r) {
          int row = row_b + r;
          Vt[((size_t)b * 256 + row) * 1024 + col] = f2bf(acc[m][n][r] + bv[row]);
        }
      }
    }
  }
}

// ---------------- w1prep: ss1 from stats1; W1s = bf16(W1*sc); h0 = b1 + W1*of ----------
__global__ __launch_bounds__(256) void w1prep(
    const float* __restrict__ W1, const float* __restrict__ b1,
    const float* __restrict__ stats1, const float* __restrict__ gamma,
    const float* __restrict__ beta,
    u16* __restrict__ W1s, float* __restrict__ h0) {
  __shared__ float ssl[512];
  const int tid = threadIdx.x;
  {
    float mean = stats1[tid] * (1.f / 16384.f);
    float var = stats1[256 + tid] * (1.f / 16384.f) - mean * mean;
    float scg = gamma[tid] * rsqrtf(var + 1e-5f);
    ssl[tid] = scg;
    ssl[256 + tid] = beta[tid] - mean * scg;
  }
  __syncthreads();
  const int lane = tid & 63, w = tid >> 6;
#pragma unroll
  for (int rr = 0; rr < 2; ++rr) {
    int f = blockIdx.x * 8 + w * 2 + rr;
    int c = lane * 4;
    float4 wv = *reinterpret_cast<const float4*>(W1 + (size_t)f * 256 + c);
    ushort4 o;
    o.x = f2bf(wv.x * ssl[c + 0]);
    o.y = f2bf(wv.y * ssl[c + 1]);
    o.z = f2bf(wv.z * ssl[c + 2]);
    o.w = f2bf(wv.w * ssl[c + 3]);
    *reinterpret_cast<ushort4*>(W1s + (size_t)f * 256 + c) = o;
    float h = wv.x * ssl[256 + c] + wv.y * ssl[257 + c] +
              wv.z * ssl[258 + c] + wv.w * ssl[259 + c];
    h += __shfl_xor(h, 1, 64);
    h += __shfl_xor(h, 2, 64);
    h += __shfl_xor(h, 4, 64);
    h += __shfl_xor(h, 8, 64);
    h += __shfl_xor(h, 16, 64);
    h += __shfl_xor(h, 32, 64);
    if (lane == 0) h0[f] = b1[f] + h;
  }
}

// ---------------- FFN1: pure gll16 GEMM, BK=64, A = SoutB bf16, B = W1s ----------------
// grid 1024: eff=(orig&7)*128+orig/8; n=eff&7, m=eff>>3
__global__ __launch_bounds__(256) void gemm_ffn1(
    const u16* __restrict__ A_,
    const u16* __restrict__ B_,
    const float* __restrict__ h0,
    const float* __restrict__ aslope,
    u16* __restrict__ H1B) {
  __shared__ u16 As[8192], Bs[8192];   // [128][64] bf16 each, TOFF2 layout
  const int tid = threadIdx.x;
  const int lane = tid & 63, w = tid >> 6;
  const int wr = w >> 1, wc = w & 1;
  const int q = lane & 15, G = lane >> 4;
  const int eff = (blockIdx.x & 7) * 128 + (blockIdx.x >> 3);
  const int m0 = (eff >> 3) * 128, n0 = (eff & 7) * 128;

  const int rl = lane >> 3, sl8 = lane & 7;
  const int ssrc = (sl8 ^ rl) * 8;  // inverse-swizzled source col (TOFF2 pairing)

  f32x4 acc[4][4] = {};
  for (int kt = 0; kt < 256; kt += 64) {
    __syncthreads();
#pragma unroll
    for (int i = 0; i < 4; ++i) {
      int rb = (i * 4 + w) * 8;
      gll16(A_ + (size_t)(m0 + rb + rl) * 256 + kt + ssrc, &As[rb * 64]);
      gll16(B_ + (size_t)(n0 + rb + rl) * 256 + kt + ssrc, &Bs[rb * 64]);
    }
    __syncthreads();
#pragma unroll
    for (int kk = 0; kk < 2; ++kk) {
      bf16x8 af[4], bfr[4];
#pragma unroll
      for (int m = 0; m < 4; ++m)
        af[m] = *reinterpret_cast<const bf16x8*>((const char*)As + TOFF2(wr * 64 + m * 16 + q, kk * 4 + G));
#pragma unroll
      for (int n = 0; n < 4; ++n)
        bfr[n] = *reinterpret_cast<const bf16x8*>((const char*)Bs + TOFF2(wc * 64 + n * 16 + q, kk * 4 + G));
#pragma unroll
      for (int m = 0; m < 4; ++m)
#pragma unroll
        for (int n = 0; n < 4; ++n)
          acc[m][n] = __builtin_amdgcn_mfma_f32_16x16x32_bf16(af[m], bfr[n], acc[m][n], 0, 0, 0);
    }
  }
  float a = aslope[0];
#pragma unroll
  for (int m = 0; m < 4; ++m) {
    int row_b = m0 + wr * 64 + m * 16 + G * 4;
#pragma unroll
    for (int n = 0; n < 4; ++n) {
      int col = n0 + wc * 64 + n * 16 + q;
      float bb = h0[col];
#pragma unroll
      for (int r = 0; r < 4; ++r) {
        float v = acc[m][n][r] + bb;
        v = (v >= 0.f) ? v : a * v;
        H1B[(size_t)(row_b + r) * 1024 + col] = f2bf(v);
      }
    }
  }
}

// ---------------- FFN2: BM=64 x BN=64 x BK=64, resid from SoutB, fused BN2 stats ------
// T2 output stored as f16 (range-safe, ~2^-11 rel) to halve epilogue traffic.
__global__ __launch_bounds__(256) void gemm_ffn2(
    const u16* __restrict__ A_,
    const u16* __restrict__ B_,
    const float* __restrict__ bias,
    const u16* __restrict__ SoutB,
    const float* __restrict__ stats1,
    const float* __restrict__ gamma,
    const float* __restrict__ beta,
    f16* __restrict__ T2,
    float* __restrict__ stats2) {
  __shared__ u16 As[4096], Bs[4096];
  __shared__ float ssl[512];
  __shared__ float sred[2][64];
  const int tid = threadIdx.x;
  const int lane = tid & 63, w = tid >> 6;
  const int wr = w >> 1, wc = w & 1;
  const int q = lane & 15, G = lane >> 4;
  const int eff = (blockIdx.x & 7) * 128 + (blockIdx.x >> 3);
  const int m0 = (eff >> 2) * 64, n0 = (eff & 3) * 64;
  {
    float mean = stats1[tid] * (1.f / 16384.f);
    float var = stats1[256 + tid] * (1.f / 16384.f) - mean * mean;
    float scg = gamma[tid] * rsqrtf(var + 1e-5f);
    ssl[tid] = scg;
    ssl[256 + tid] = beta[tid] - mean * scg;
  }
  if (tid < 64) { sred[0][tid] = 0.f; sred[1][tid] = 0.f; }

  const int rl = lane >> 3, sl8 = lane & 7;
  const int ssrc = (sl8 ^ rl) * 8;

  f32x4 acc[2][2] = {};
  for (int kt = 0; kt < 1024; kt += 64) {
    __syncthreads();
#pragma unroll
    for (int i = 0; i < 2; ++i) {
      int rb = (i * 4 + w) * 8;
      gll16(A_ + (size_t)(m0 + rb + rl) * 1024 + kt + ssrc, &As[rb * 64]);
      gll16(B_ + (size_t)(n0 + rb + rl) * 1024 + kt + ssrc, &Bs[rb * 64]);
    }
    __syncthreads();
#pragma unroll
    for (int kk = 0; kk < 2; ++kk) {
      bf16x8 af[2], bf2[2];
#pragma unroll
      for (int m = 0; m < 2; ++m)
        af[m] = *reinterpret_cast<const bf16x8*>((const char*)As + TOFF2(wr * 32 + m * 16 + q, kk * 4 + G));
#pragma unroll
      for (int n = 0; n < 2; ++n)
        bf2[n] = *reinterpret_cast<const bf16x8*>((const char*)Bs + TOFF2(wc * 32 + n * 16 + q, kk * 4 + G));
#pragma unroll
      for (int m = 0; m < 2; ++m)
#pragma unroll
        for (int n = 0; n < 2; ++n)
          acc[m][n] = __builtin_amdgcn_mfma_f32_16x16x32_bf16(af[m], bf2[n], acc[m][n], 0, 0, 0);
    }
  }
  float s1a[2] = {0.f, 0.f}, s2a[2] = {0.f, 0.f};
#pragma unroll
  for (int m = 0; m < 2; ++m) {
    int row_b = m0 + wr * 32 + m * 16 + G * 4;
#pragma unroll
    for (int n = 0; n < 2; ++n) {
      int col = n0 + wc * 32 + n * 16 + q;
      float bb = bias[col];
      float sc_ = ssl[col], of_ = ssl[256 + col];
#pragma unroll
      for (int r = 0; r < 4; ++r) {
        int row = row_b + r;
        float resid = bf2f(SoutB[(size_t)row * 256 + col]) * sc_ + of_;
        float v = acc[m][n][r] + bb + resid;
        T2[(size_t)row * 256 + col] = (f16)v;
        s1a[n] += v;
        s2a[n] += v * v;
      }
    }
  }
#pragma unroll
  for (int n = 0; n < 2; ++n) {
    float a1 = s1a[n];
    a1 += __shfl_xor(a1, 16, 64);
    a1 += __shfl_xor(a1, 32, 64);
    float a2 = s2a[n];
    a2 += __shfl_xor(a2, 16, 64);
    a2 += __shfl_xor(a2, 32, 64);
    if (lane < 16) {
      atomicAdd(&sred[0][wc * 32 + n * 16 + lane], a1);
      atomicAdd(&sred[1][wc * 32 + n * 16 + lane], a2);
    }
  }
  __syncthreads();
  if (tid < 64) {
    atomicAdd(&stats2[n0 + tid], sred[0][tid]);
    atomicAdd(&stats2[256 + n0 + tid], sred[1][tid]);
  }
}

// ---------------- final BN (inline from stats2) + transpose [T,C](f16) -> [B,C,N] ------
__global__ __launch_bounds__(256) void bn_final_out(const f16* __restrict__ T2,
                                                    const float* __restrict__ stats2,
                                                    const float* __restrict__ gamma,
                                                    const float* __restrict__ beta,
                                                    float* __restrict__ out) {
  __shared__ float tile[32][33];
  int n0 = (blockIdx.x & 31) * 32;
  int b = blockIdx.x >> 5;
  int c0 = blockIdx.y * 32;
  int tx = threadIdx.x, ty = threadIdx.y;
  int c = c0 + tx;
  float mean = stats2[c] * (1.f / 16384.f);
  float var = stats2[256 + c] * (1.f / 16384.f) - mean * mean;
  float scg = gamma[c] * rsqrtf(var + 1e-5f);
  float off = beta[c] - mean * scg;
#pragma unroll
  for (int j = 0; j < 4; ++j) {
    int r = ty + j * 8;
    float v = (float)T2[((size_t)b * 1024 + n0 + r) * 256 + c];
    tile[r][tx] = v * scg + off;
  }
  __syncthreads();
#pragma unroll
  for (int j = 0; j < 4; ++j) {
    int cc = c0 + ty + j * 8;
    out[((size_t)b * 256 + cc) * 1024 + n0 + tx] = tile[tx][ty + j * 8];
  }
}

// ---------------- fused flash attention: 8 waves / 128 q-rows, no-shift softmax --------
// residual reconstructed from XtbH/XtbL (token-major, same gi as SoutB; x never re-read)
#define SWZ(row, bcol) ((bcol) ^ (((row) & 7) << 4))
__global__ __launch_bounds__(512, 4) void attn_kernel(const u16* __restrict__ QKh,
                                                      const u16* __restrict__ QKl,
                                                      const u16* __restrict__ Vt,
                                                      const u16* __restrict__ XtbH,
                                                      const u16* __restrict__ XtbL,
                                                      u16* __restrict__ SoutB,
                                                      float* __restrict__ stats) {
  __shared__ u16 Kh[2][4096], Vs[2][4096];
  __shared__ float sred[2][64];
  const int tid = threadIdx.x, lane = tid & 63, w = tid >> 6;
  const int hb = blockIdx.x, h = hb & 3, b = hb >> 2;
  const size_t tb = (size_t)b * 1024;
  const int qrow0 = blockIdx.y * 128 + w * 16;
  const int q = lane & 15, G = lane >> 4;

  if (tid < 64) { sred[0][tid] = 0.f; sred[1][tid] = 0.f; }

  bf16x8 qh[2], ql[2];
#pragma unroll
  for (int kk = 0; kk < 2; ++kk) {
    size_t ro = (tb + qrow0 + q) * 512 + h * 64 + kk * 32 + G * 8;
    qh[kk] = *reinterpret_cast<const bf16x8*>(QKh + ro);
    ql[kk] = *reinterpret_cast<const bf16x8*>(QKl + ro);
  }

  f32x4 oacc[4] = {};
  float lsum = 0.f;

  const int sr = tid >> 3;
  const int c7 = tid & 7;
  const int dstb = sr * 128 + SWZ(sr, c7 << 4);
  const size_t kbase = (tb + sr) * 512 + 256 + h * 64 + c7 * 8;
  const int vb0 = 32 * (c7 >> 2) + 8 * ((2 * c7) & 3) + 4 * ((c7 >> 1) & 1);
  const int vx0 = (vb0 * 2) ^ ((sr & 7) << 4);
  const int vx1 = (vb0 * 2 + 16) ^ ((sr & 7) << 4);
  const size_t vbase = ((size_t)b * 256 + h * 64 + sr) * 1024 + c7 * 8;

  uint4 rk = *reinterpret_cast<const uint4*>(QKh + kbase);
  uint4 rv = *reinterpret_cast<const uint4*>(Vt + vbase);
  *reinterpret_cast<uint4*>((char*)Kh[0] + dstb) = rk;
  {
    uint2 lo = {rv.x, rv.y}, hi = {rv.z, rv.w};
    *reinterpret_cast<uint2*>((char*)Vs[0] + sr * 128 + vx0) = lo;
    *reinterpret_cast<uint2*>((char*)Vs[0] + sr * 128 + vx1) = hi;
  }
  __syncthreads();

  int cur = 0;
  for (int kt = 0; kt < 16; ++kt) {
    if (kt < 15) {
      rk = *reinterpret_cast<const uint4*>(QKh + kbase + (size_t)(kt + 1) * 32768);
      rv = *reinterpret_cast<const uint4*>(Vt + vbase + (size_t)(kt + 1) * 64);
    }

    f32x4 sc[4] = {};
    __builtin_amdgcn_s_setprio(1);
#pragma unroll
    for (int kk = 0; kk < 2; ++kk)
#pragma unroll
      for (int n = 0; n < 4; ++n) {
        int krow = n * 16 + q;
        int kb_ = krow * 128 + SWZ(krow, kk * 64 + G * 16);
        bf16x8 akh = *reinterpret_cast<const bf16x8*>((const char*)Kh[cur] + kb_);
        sc[n] = __builtin_amdgcn_mfma_f32_16x16x32_bf16(akh, qh[kk], sc[n], 0, 0, 0);
        sc[n] = __builtin_amdgcn_mfma_f32_16x16x32_bf16(akh, ql[kk], sc[n], 0, 0, 0);
      }
    __builtin_amdgcn_s_setprio(0);

    float lt = 0.f;
#pragma unroll
    for (int n = 0; n < 4; ++n)
#pragma unroll
      for (int r = 0; r < 4; ++r) {
        float p = exp2_fast(sc[n][r]);
        sc[n][r] = p;
        lt += p;
      }
    lsum += lt;
    bf16x8 pa[2];
    {
      uint4 pw0, pw1;
      pw0.x = cvt_pk_bf16(sc[0][0], sc[0][1]);
      pw0.y = cvt_pk_bf16(sc[0][2], sc[0][3]);
      pw0.z = cvt_pk_bf16(sc[1][0], sc[1][1]);
      pw0.w = cvt_pk_bf16(sc[1][2], sc[1][3]);
      pw1.x = cvt_pk_bf16(sc[2][0], sc[2][1]);
      pw1.y = cvt_pk_bf16(sc[2][2], sc[2][3]);
      pw1.z = cvt_pk_bf16(sc[3][0], sc[3][1]);
      pw1.w = cvt_pk_bf16(sc[3][2], sc[3][3]);
      pa[0] = *reinterpret_cast<bf16x8*>(&pw0);
      pa[1] = *reinterpret_cast<bf16x8*>(&pw1);
    }
    __builtin_amdgcn_s_setprio(1);
#pragma unroll
    for (int kk = 0; kk < 2; ++kk)
#pragma unroll
      for (int dn = 0; dn < 4; ++dn) {
        int vrow = dn * 16 + q;
        int vb_ = vrow * 128 + SWZ(vrow, kk * 64 + G * 16);
        bf16x8 vv = *reinterpret_cast<const bf16x8*>((const char*)Vs[cur] + vb_);
        oacc[dn] = __builtin_amdgcn_mfma_f32_16x16x32_bf16(pa[kk], vv, oacc[dn], 0, 0, 0);
      }
    __builtin_amdgcn_s_setprio(0);
    if (kt < 15) {
      *reinterpret_cast<uint4*>((char*)Kh[cur ^ 1] + dstb) = rk;
      uint2 lo = {rv.x, rv.y}, hi = {rv.z, rv.w};
      *reinterpret_cast<uint2*>((char*)Vs[cur ^ 1] + sr * 128 + vx0) = lo;
      *reinterpret_cast<uint2*>((char*)Vs[cur ^ 1] + sr * 128 + vx1) = hi;
    }
    __syncthreads();
    cur ^= 1;
  }
  float lf = lsum;
  lf += __shfl_xor(lf, 16, 64);
  lf += __shfl_xor(lf, 32, 64);
  float rinv[4];
#pragma unroll
  for (int r = 0; r < 4; ++r) rinv[r] = 1.f / __shfl(lf, G * 4 + r, 64);

  const int row0 = qrow0 + G * 4;
  float s1a[4] = {0.f, 0.f, 0.f, 0.f}, s2a[4] = {0.f, 0.f, 0.f, 0.f};
#pragma unroll
  for (int dn = 0; dn < 4; ++dn) {
    int col = dn * 16 + q;
#pragma unroll
    for (int r = 0; r < 4; ++r) {
      size_t gi = (tb + row0 + r) * 256 + h * 64 + col;
      float xv = bf2f(XtbH[gi]) + bf2f(XtbL[gi]);
      float v = oacc[dn][r] * rinv[r] + xv;
      SoutB[gi] = f2bf(v);
      s1a[dn] += v;
      s2a[dn] += v * v;
    }
  }
#pragma unroll
  for (int dn = 0; dn < 4; ++dn) {
    float a1 = s1a[dn];
    a1 += __shfl_xor(a1, 16, 64);
    a1 += __shfl_xor(a1, 32, 64);
    float a2 = s2a[dn];
    a2 += __shfl_xor(a2, 16, 64);
    a2 += __shfl_xor(a2, 32, 64);
    if (lane < 16) {
      atomicAdd(&sred[0][dn * 16 + lane], a1);
      atomicAdd(&sred[1][dn * 16 + lane], a2);
    }
  }
  __syncthreads();
  if (tid < 64) {
    atomicAdd(&stats[h * 64 + tid], sred[0][tid]);
    atomicAdd(&stats[256 + h * 64 + tid], sred[1][tid]);
  }
}

// ---------------- launch ----------------
extern "C" void kernel_launch(void* const* d_in, const int* in_sizes, int n_in,
                              void* d_out, int out_size, void* d_ws, size_t ws_size,
                              hipStream_t stream) {
  const float* x = (const float*)d_in[0];
  const float* Wq = (const float*)d_in[1];
  const float* bq = (const float*)d_in[2];
  const float* Wk = (const float*)d_in[3];
  const float* bk = (const float*)d_in[4];
  const float* Wv = (const float*)d_in[5];
  const float* bv = (const float*)d_in[6];
  const float* gamma = (const float*)d_in[7];
  const float* beta = (const float*)d_in[8];
  const float* W1 = (const float*)d_in[9];
  const float* b1 = (const float*)d_in[10];
  const float* a = (const float*)d_in[11];
  const float* W2 = (const float*)d_in[12];
  const float* b2 = (const float*)d_in[13];
  float* out = (float*)d_out;

  char* wsb = (char*)d_ws;
  const size_t MB = 1ull << 20;
  u16* XtbH = (u16*)(wsb + 0 * MB);        // 8MB; region [0,8) reused as T2(f16) after attn
  u16* XtbL = (u16*)(wsb + 8 * MB);        // 8MB
  f16* T2 = (f16*)(wsb + 0 * MB);          // 8MB f16 (alias XtbH; written by ffn2, after attn)
  u16* SoutB = (u16*)(wsb + 16 * MB);      // 8MB (raw o+x in bf16)
  u16* QKh = (u16*)(wsb + 32 * MB);        // 16MB; [32,64) reused as H1B after attn
  u16* QKl = (u16*)(wsb + 48 * MB);        // 16MB
  u16* Vt = (u16*)(wsb + 64 * MB);         // 8MB
  char* wp = wsb + 72 * MB;
  u16* WallH = (u16*)(wp);                 // 256KB
  u16* WallL = (u16*)(wp + 262144);        // 256KB
  u16* WvH = (u16*)(wp + 524288);          // 128KB
  u16* WvL = (u16*)(wp + 655360);          // 128KB
  u16* W1s = (u16*)(wp + 786432);          // 512KB (BN-scaled W1, by w1prep)
  u16* W2b = (u16*)(wp + 1310720);         // 512KB
  float* bqk = (float*)(wp + 1835008);     // 2KB
  float* stats = (float*)(wp + 1837056);   // 8KB: stats1 | pad | stats2 | pad
  float* h0 = (float*)(wp + 1845248);      // 4KB
  if (ws_size < 73 * MB) return;

  u16* H1B = QKh;    // [T,1024] bf16, after attn
  float* stats2 = stats + 1024;

  // fused x-transpose + weight prep + stats zeroing (no separate memset dispatch)
  prep_all<<<5120, 256, 0, stream>>>(x, Wq, Wk, Wv, bq, bk, W2,
                                     XtbH, XtbL, WallH, WallL, WvH, WvL, W2b, bqk, stats);
  // fused QK projection (Q pre-scaled by log2e) + V projection transposed
  gemm_qkvt<<<768, 256, 0, stream>>>(XtbH, XtbL, WallH, WallL, bqk, QKh, QKl,
                                     WvH, WvL, bv, Vt);
  // attention + residual (from XtbH/L) + BN1 stats: 8-wave blocks
  attn_kernel<<<dim3(64, 8), 512, 0, stream>>>(QKh, QKl, Vt, XtbH, XtbL, SoutB, stats);
  // fold BN1 into W1: W1s = bf16(W1*sc), h0 = b1 + W1*of
  w1prep<<<128, 256, 0, stream>>>(W1, b1, stats, gamma, beta, W1s, h0);
  // FFN1: pure gll16 GEMM BK=64 (A=SoutB, B=W1s), bias h0, PReLU
  gemm_ffn1<<<1024, 256, 0, stream>>>(SoutB, W1s, h0, a, H1B);
  // FFN2: bias + BN1(resid from SoutB) + BN2 stats -> T2 (f16)
  gemm_ffn2<<<1024, 256, 0, stream>>>(H1B, W2b, b2, SoutB, stats, gamma, beta, T2, stats2);
  // BN2 apply (inline finalize) + transpose out
  bn_final_out<<<dim3(512, 8), dim3(32, 8), 0, stream>>>(T2, stats2, gamma, beta, out);
}